// Round 4
// baseline (1851.458 us; speedup 1.0000x reference)
//
#include <hip/hip_runtime.h>
#include <hip/hip_fp16.h>

typedef _Float16 f16;
typedef _Float16 f16x8 __attribute__((ext_vector_type(8)));
typedef _Float16 f16x4 __attribute__((ext_vector_type(4)));
typedef float f32x4 __attribute__((ext_vector_type(4)));

#define B_ 1024
#define T_ 128
#define F_ 9
#define H_ 256
#define P_ 2048

#define AL(p) __hip_atomic_load((p), __ATOMIC_RELAXED, __HIP_MEMORY_SCOPE_AGENT)
#define AS(p, v) __hip_atomic_store((p), (v), __ATOMIC_RELAXED, __HIP_MEMORY_SCOPE_AGENT)

// ---------------- helpers ----------------
__device__ __forceinline__ float sigf(float x) { return 1.f / (1.f + __expf(-x)); }
__device__ __forceinline__ float tanh_(float x) {
  float a = fminf(fabsf(x), 12.f);
  float e = __expf(2.f * a);
  float r = 1.f - 2.f / (e + 1.f);
  return copysignf(r, x);
}

__device__ __forceinline__ float blk_sum(float v) {
  __shared__ float sh[8];
  int lane = threadIdx.x & 63, w = threadIdx.x >> 6;
  int nw = blockDim.x >> 6;
#pragma unroll
  for (int o = 32; o > 0; o >>= 1) v += __shfl_xor(v, o, 64);
  __syncthreads();
  if (lane == 0) sh[w] = v;
  __syncthreads();
  float t = 0.f;
  for (int i = 0; i < nw; i++) t += sh[i];
  return t;
}

// ---------------- generic fp16 MFMA GEMM ----------------
__global__ __launch_bounds__(256) void gemm_f16(
    const f16* __restrict__ A, int lda,
    const f16* __restrict__ Bt, int ldb,
    const float* __restrict__ bias,
    f16* __restrict__ o16, int ldo16,
    float* __restrict__ o32, int ldo32,
    int M, int N, int K)
{
  __shared__ __align__(16) f16 As[128][40];
  __shared__ __align__(16) f16 Bs[128][40];
  const int tid = threadIdx.x;
  const int lane = tid & 63, wave = tid >> 6;
  const int wr = (wave >> 1) * 64, wc = (wave & 1) * 64;
  const int q = lane >> 4, l15 = lane & 15;
  const int bm = blockIdx.x * 128, bn = blockIdx.y * 128;

  f32x4 acc[4][4];
#pragma unroll
  for (int i = 0; i < 4; i++)
#pragma unroll
    for (int j = 0; j < 4; j++) acc[i][j] = (f32x4){0.f, 0.f, 0.f, 0.f};

  for (int k0 = 0; k0 < K; k0 += 32) {
#pragma unroll
    for (int c = 0; c < 2; ++c) {
      int ch = tid + c * 256;
      int row = ch >> 2, kh = (ch & 3) * 8;
      *(f16x8*)&As[row][kh] = *(const f16x8*)&A[(size_t)(bm + row) * lda + k0 + kh];
      *(f16x8*)&Bs[row][kh] = *(const f16x8*)&Bt[(size_t)(bn + row) * ldb + k0 + kh];
    }
    __syncthreads();
    f16x8 af[4], bf[4];
#pragma unroll
    for (int tm = 0; tm < 4; tm++) af[tm] = *(const f16x8*)&As[wr + tm * 16 + l15][q * 8];
#pragma unroll
    for (int tn = 0; tn < 4; tn++) bf[tn] = *(const f16x8*)&Bs[wc + tn * 16 + l15][q * 8];
#pragma unroll
    for (int tm = 0; tm < 4; tm++)
#pragma unroll
      for (int tn = 0; tn < 4; tn++)
        acc[tm][tn] = __builtin_amdgcn_mfma_f32_16x16x32_f16(af[tm], bf[tn], acc[tm][tn], 0, 0, 0);
    __syncthreads();
  }
#pragma unroll
  for (int tm = 0; tm < 4; tm++) {
#pragma unroll
    for (int tn = 0; tn < 4; tn++) {
      int colg = bn + wc + tn * 16 + l15;
      float bv = bias ? bias[colg] : 0.f;
#pragma unroll
      for (int r = 0; r < 4; r++) {
        int rowg = bm + wr + tm * 16 + q * 4 + r;
        float v = acc[tm][tn][r] + bv;
        if (o32) o32[(size_t)rowg * ldo32 + colg] = v;
        if (o16) o16[(size_t)rowg * ldo16 + colg] = (f16)v;
      }
    }
  }
}

// ---------------- LSTM v5: poison-validate + two-group interleave --------
// A group's weights (1 MB) exceed one CU's 512 KB register file, so a group
// spans 4 blocks at 1 wave/SIMD -> cross-block exchange through the MALL is
// structural. v5 hides that latency instead of shortening it: each block
// owns TWO independent row-groups (same weight slice, so no extra weight
// regs) and interleaves them -- while group A's handshake is in flight the
// block computes group B, and vice versa.
//
// Sync protocol = R2's poison-validate (passed correctness): hout is a
// separate buffer pre-poisoned 0xFF (f16 0xFFFF = NaN, unforgeable since
// h = sig*tanh of finite is finite); every word is written exactly once via
// atomic u64 stores, so a non-poison read IS the final value. R2's two perf
// bugs fixed: (1) spin-storm -- speculative loads are issued ONCE right
// after storing own h; the check happens a full other-group phase (~2000cy)
// later when flights have landed; retries sleep(8). (2) exposed latency --
// spec-load and peer-store flights overlap the other group's compute.
// 2 barriers per group-step; each LDS buffer's reuse is separated by >=2
// barriers of the other group's phase.
__device__ __forceinline__ void lstm_group_step(
    int t, const f16* __restrict__ xin, f16* __restrict__ hout,
    size_t rowbase, size_t storebase,
    const f16x8 (&bf)[4][16], const float (&bv)[4],
    float (&cst)[4], f16x8& xr0, f16x8& xr1,
    unsigned long long& s0, unsigned long long& s1,
    unsigned long long& s2, unsigned long long& s3,
    f16 (*apf)[64][8], f16 (*htile)[64],
    int tid, int lane, int w, int q, int l15)
{
  const unsigned long long POI = 0xFFFFFFFFFFFFFFFFull;
  const f16x8 zv = {(f16)0, (f16)0, (f16)0, (f16)0, (f16)0, (f16)0, (f16)0, (f16)0};

  // ---- validate h_{t-1}: spec regs were loaded one iteration ago ----
  f16x8 h0 = zv, h1 = zv;
  if (t > 0) {
    union { unsigned long long u[2]; f16x8 v; } ua, ub;
    ua.u[0] = s0; ua.u[1] = s1; ub.u[0] = s2; ub.u[1] = s3;
    const unsigned long long* p0 =
        (const unsigned long long*)&hout[rowbase + (size_t)(t - 1) * 256 + (size_t)w * 32];
    const unsigned long long* p1 =
        (const unsigned long long*)&hout[rowbase + (size_t)(t - 1) * 256 + (size_t)(w + 4) * 32];
    int it = 0;
    while ((ua.u[0] == POI) | (ua.u[1] == POI) | (ub.u[0] == POI) | (ub.u[1] == POI)) {
      __builtin_amdgcn_s_sleep(8);
      ua.u[0] = AL(p0); ua.u[1] = AL(p0 + 1);
      ub.u[0] = AL(p1); ub.u[1] = AL(p1 + 1);
      if (++it > (1 << 22)) break;   // bailout: wrong answer beats a hang
    }
    h0 = ua.v; h1 = ub.v;
  }
  // ---- stage x_t (prefetch regs) + h_{t-1} into A-frag LDS ----
  *(f16x8*)&apf[w][lane][0]      = xr0;
  *(f16x8*)&apf[w + 4][lane][0]  = xr1;
  *(f16x8*)&apf[8 + w][lane][0]  = h0;
  *(f16x8*)&apf[12 + w][lane][0] = h1;
  __syncthreads();                 // S1: apf staged

  // ---- compute: 64 MFMAs, B-operands resident in registers ----
  f32x4 acc[4];
#pragma unroll
  for (int g = 0; g < 4; g++) acc[g] = (f32x4){0.f, 0.f, 0.f, 0.f};
#pragma unroll
  for (int k = 0; k < 16; k++) {
    f16x8 a = *(const f16x8*)&apf[k][lane][0];
#pragma unroll
    for (int g = 0; g < 4; g++)
      acc[g] = __builtin_amdgcn_mfma_f32_16x16x32_f16(a, bf[g][k], acc[g], 0, 0, 0);
  }
  // prefetch x_{t+1} (xin read-only; no clobber hazard)
  if (t + 1 < T_) {
    xr0 = *(const f16x8*)&xin[rowbase + (size_t)(t + 1) * 256 + (size_t)w * 32];
    xr1 = *(const f16x8*)&xin[rowbase + (size_t)(t + 1) * 256 + (size_t)(w + 4) * 32];
  }
  // gate math (lane: rows q*4+r of its 16-row group)
  f16 hn[4];
#pragma unroll
  for (int r = 0; r < 4; r++) {
    float ip = acc[0][r] + bv[0];
    float fp = acc[1][r] + bv[1];
    float gp = acc[2][r] + bv[2];
    float op = acc[3][r] + bv[3];
    float cn = sigf(fp) * cst[r] + sigf(ip) * tanh_(gp);
    cst[r] = cn;
    hn[r] = (f16)(sigf(op) * tanh_(cn));
  }
  // htile reuse is safe: its last readers (store phase, prev iteration)
  // are >=2 barriers back (S3 prev + other group's S1/S3).
#pragma unroll
  for (int r = 0; r < 4; r++) htile[q * 4 + r][w * 16 + l15] = hn[r];
  __syncthreads();                 // S3: htile ready
  {                                // publish h_t: one atomic u64 per thread
    int row = tid >> 4, c4 = (tid & 15) * 4;
    union { unsigned long long u; f16x4 v; } uh;
    uh.v = *(const f16x4*)&htile[row][c4];
    AS((unsigned long long*)&hout[storebase + ((size_t)row * T_ + t) * 256 + c4], uh.u);
  }
  // ---- speculative loads for h_t (needed next iteration) ----
  // Issued now; checked after the other group's full phase -> flight hidden.
  if (t + 1 < T_) {
    const unsigned long long* p0 =
        (const unsigned long long*)&hout[rowbase + (size_t)t * 256 + (size_t)w * 32];
    const unsigned long long* p1 =
        (const unsigned long long*)&hout[rowbase + (size_t)t * 256 + (size_t)(w + 4) * 32];
    s0 = AL(p0); s1 = AL(p0 + 1);
    s2 = AL(p1); s3 = AL(p1 + 1);
  }
}

// grid 128 = 4 col-slices x 32 group-pairs; block owns groups gA and gA+32.
__global__ __launch_bounds__(256, 1) void lstm2(
    const f16* __restrict__ xin,     // previous layer h (read-only)
    f16* __restrict__ hout,          // pre-poisoned 0xFF, written via atomics
    const f16* __restrict__ wpk,     // packed [s(4)][w(4)][g(4)][k(16)][lane(64)][8]
    const float* __restrict__ bias)
{
  __shared__ __align__(16) f16 apf[2][16][64][8];   // 32 KB
  __shared__ __align__(16) f16 htile[2][16][64];    // 4 KB
  const int tid = threadIdx.x;
  const int lane = tid & 63, w = tid >> 6;
  const int q = lane >> 4, l15 = lane & 15;
  const int s = blockIdx.x >> 5;               // col-slice 0..3
  const int gA = blockIdx.x & 31, gB = gA + 32;
  const int m0A = gA * 16, m0B = gB * 16;

  // ---- weight slice into registers: 64 x f16x8 = 256 regs/lane ----
  f16x8 bf[4][16];
  {
    const f16* wbase = wpk + (((size_t)(s * 4 + w) * 4) * 16) * 512 + lane * 8;
#pragma unroll
    for (int g = 0; g < 4; g++)
#pragma unroll
      for (int k = 0; k < 16; k++)
        bf[g][k] = *(const f16x8*)(wbase + (size_t)(g * 16 + k) * 512);
  }
  float bv[4];
#pragma unroll
  for (int g = 0; g < 4; g++) bv[g] = bias[g * 256 + s * 64 + w * 16 + l15];

  const int srow = lane & 15, scb = lane >> 4;
  const size_t rowbaseA = ((size_t)(m0A + srow) * T_) * 256 + scb * 8;
  const size_t rowbaseB = ((size_t)(m0B + srow) * T_) * 256 + scb * 8;
  const size_t storebaseA = ((size_t)m0A * T_) * 256 + s * 64;
  const size_t storebaseB = ((size_t)m0B * T_) * 256 + s * 64;

  f16x8 xrA0 = *(const f16x8*)&xin[rowbaseA + (size_t)w * 32];
  f16x8 xrA1 = *(const f16x8*)&xin[rowbaseA + (size_t)(w + 4) * 32];
  f16x8 xrB0 = *(const f16x8*)&xin[rowbaseB + (size_t)w * 32];
  f16x8 xrB1 = *(const f16x8*)&xin[rowbaseB + (size_t)(w + 4) * 32];
  float cstA[4] = {0.f, 0.f, 0.f, 0.f}, cstB[4] = {0.f, 0.f, 0.f, 0.f};
  unsigned long long sA0 = 0, sA1 = 0, sA2 = 0, sA3 = 0;
  unsigned long long sB0 = 0, sB1 = 0, sB2 = 0, sB3 = 0;

  for (int t = 0; t < T_; ++t) {
    lstm_group_step(t, xin, hout, rowbaseA, storebaseA, bf, bv, cstA,
                    xrA0, xrA1, sA0, sA1, sA2, sA3, apf[0], htile[0],
                    tid, lane, w, q, l15);
    lstm_group_step(t, xin, hout, rowbaseB, storebaseB, bf, bv, cstB,
                    xrB0, xrB1, sB0, sB1, sB2, sB3, apf[1], htile[1],
                    tid, lane, w, q, l15);
  }
}

// ---------------- VSN, two-phase ----------------
__global__ __launch_bounds__(256) void vsn_w_kernel(
    const float* __restrict__ x, const float* __restrict__ selw,
    const float* __restrict__ selb, float* __restrict__ wb)
{
  int pos = blockIdx.x * 256 + threadIdx.x;
  const float* xr = x + (size_t)pos * F_;
  float xv[F_];
#pragma unroll
  for (int f = 0; f < F_; f++) xv[f] = xr[f];
  float wv[F_]; float mx = -1e30f;
#pragma unroll
  for (int f = 0; f < F_; f++) {
    float s = selb[f];
#pragma unroll
    for (int f2 = 0; f2 < F_; f2++) s += xv[f2] * selw[f * F_ + f2];
    wv[f] = s; mx = fmaxf(mx, s);
  }
  float se = 0.f;
#pragma unroll
  for (int f = 0; f < F_; f++) { wv[f] = __expf(wv[f] - mx); se += wv[f]; }
  float inv = 1.f / se;
  float* o = wb + (size_t)pos * 18;
#pragma unroll
  for (int f = 0; f < F_; f++) {
    float wt = wv[f] * inv;
    o[f] = wt; o[9 + f] = wt * xv[f];
  }
}

__global__ __launch_bounds__(256) void vsn_h_kernel(
    const float* __restrict__ wb, const float* __restrict__ embw,
    const float* __restrict__ embb, f16* __restrict__ hout)
{
  int j = threadIdx.x;
  float ew[F_], eb[F_];
#pragma unroll
  for (int f = 0; f < F_; f++) { ew[f] = embw[f * H_ + j]; eb[f] = embb[f * H_ + j]; }
  for (int i = 0; i < 128; i++) {
    size_t pos = blockIdx.x + (size_t)i * 1024;
    const float* w = wb + pos * 18;
    float h = 0.f;
#pragma unroll
    for (int f = 0; f < F_; f++) h += w[9 + f] * ew[f] + w[f] * eb[f];
    hout[pos * H_ + j] = (f16)h;
  }
}

// ---------------- attention in h-space ----------------
__global__ __launch_bounds__(256) void qk_kernel(
    const float* __restrict__ qbuf, const float* __restrict__ attn_in_w,
    float* __restrict__ qk)
{
  __shared__ float qs[256];
  int b = blockIdx.x, j = threadIdx.x;
  qs[j] = qbuf[(size_t)b * 256 + j];
  __syncthreads();
#pragma unroll
  for (int h = 0; h < 4; h++) {
    float acc = 0.f;
    for (int d = 0; d < 64; d++)
      acc += qs[h * 64 + d] * attn_in_w[(size_t)(256 + h * 64 + d) * 256 + j];
    qk[((size_t)b * 4 + h) * 256 + j] = acc * 0.125f;
  }
}

__global__ __launch_bounds__(256) void attnpool_kernel(
    const f16* __restrict__ hseq, const float* __restrict__ qk,
    float* __restrict__ hbar)
{
  __shared__ __align__(16) f16 hs[T_][264];
  __shared__ float qks[4][256];
  __shared__ float ps[4][T_];
  int b = blockIdx.x, tid = threadIdx.x;
  for (int i = tid; i < T_ * 32; i += 256) {
    int row = i >> 5, cc = (i & 31) * 8;
    *(f16x8*)&hs[row][cc] = *(const f16x8*)&hseq[((size_t)b * T_ + row) * 256 + cc];
  }
  for (int i = tid; i < 1024; i += 256) qks[i >> 8][i & 255] = qk[(size_t)b * 1024 + i];
  __syncthreads();
  if (tid < T_) {
    float s[4] = {0.f, 0.f, 0.f, 0.f};
    for (int cc = 0; cc < 32; cc++) {
      f16x8 v = *(const f16x8*)&hs[tid][cc * 8];
#pragma unroll
      for (int h = 0; h < 4; h++) {
        float a = 0.f;
#pragma unroll
        for (int j = 0; j < 8; j++) a += qks[h][cc * 8 + j] * (float)v[j];
        s[h] += a;
      }
    }
#pragma unroll
    for (int h = 0; h < 4; h++) ps[h][tid] = s[h];
  }
  __syncthreads();
  {
    int w = tid >> 6, l = tid & 63;
    float a = ps[w][l], bb = ps[w][l + 64];
    float m = fmaxf(a, bb);
#pragma unroll
    for (int o = 32; o > 0; o >>= 1) m = fmaxf(m, __shfl_xor(m, o, 64));
    float e0 = __expf(a - m), e1 = __expf(bb - m);
    float se = e0 + e1;
#pragma unroll
    for (int o = 32; o > 0; o >>= 1) se += __shfl_xor(se, o, 64);
    float inv = 1.f / se;
    ps[w][l] = e0 * inv; ps[w][l + 64] = e1 * inv;
  }
  __syncthreads();
  int j = tid;
  float acc[4] = {0.f, 0.f, 0.f, 0.f};
  for (int t = 0; t < T_; t++) {
    float hv = (float)hs[t][j];
#pragma unroll
    for (int h = 0; h < 4; h++) acc[h] += ps[h][t] * hv;
  }
#pragma unroll
  for (int h = 0; h < 4; h++) hbar[((size_t)b * 4 + h) * 256 + j] = acc[h];
}

__global__ __launch_bounds__(256) void vproj_kernel(
    const float* __restrict__ hbar, const float* __restrict__ attn_in_w,
    const float* __restrict__ attn_in_b, f16* __restrict__ aob)
{
  __shared__ float hb[4][256];
  int b = blockIdx.x, tid = threadIdx.x;
  for (int i = tid; i < 1024; i += 256) hb[i >> 8][i & 255] = hbar[(size_t)b * 1024 + i];
  __syncthreads();
  int d = tid, h = d >> 6;
  const float4* wr = (const float4*)(attn_in_w + (size_t)(512 + d) * 256);
  float acc = 0.f;
  for (int cc = 0; cc < 64; cc++) {
    float4 w4 = wr[cc];
    acc += w4.x * hb[h][cc * 4] + w4.y * hb[h][cc * 4 + 1]
         + w4.z * hb[h][cc * 4 + 2] + w4.w * hb[h][cc * 4 + 3];
  }
  aob[(size_t)b * 256 + d] = (f16)(acc + attn_in_b[512 + d]);
}

// ---------------- GNN prep ----------------
__global__ __launch_bounds__(256) void deg_adjn_kernel(
    const float* __restrict__ adj, const int* __restrict__ sku,
    f16* __restrict__ adjn)
{
  int bp = blockIdx.x;
  int p = sku[bp];
  int tid = threadIdx.x;
  float s = 0.f;
  for (int j = tid; j < P_; j += 256) s += adj[(size_t)p * P_ + j];
  float tot = blk_sum(s);
  float inv = 1.f / fmaxf(tot, 1e-6f);
  for (int b = tid; b < B_; b += 256)
    adjn[(size_t)bp * B_ + b] = (f16)(adj[(size_t)p * P_ + sku[b]] * inv);
}

__global__ void transpose_kernel(const float* __restrict__ hid, f16* __restrict__ hT)
{
  int i = blockIdx.x * 256 + threadIdx.x;
  int b = i >> 8, j = i & 255;
  hT[(size_t)j * B_ + b] = (f16)hid[i];
}

__global__ __launch_bounds__(256) void gelu_ln_kernel(
    const float* __restrict__ pre, const float* __restrict__ lg,
    const float* __restrict__ lb, float* __restrict__ enr,
    f16* __restrict__ hidcat)
{
  int row = blockIdx.x, j = threadIdx.x;
  float xv = pre[row * 256 + j];
  float ge = 0.5f * xv * (1.f + erff(xv * 0.70710678118654752f));
  float mu = blk_sum(ge) * (1.f / 256.f);
  float d = ge - mu;
  float var = blk_sum(d * d) * (1.f / 256.f);
  float y = d * rsqrtf(var + 1e-5f) * lg[j] + lb[j];
  enr[row * 256 + j] = y;
  hidcat[row * 512 + 256 + j] = (f16)y;
}

__global__ __launch_bounds__(256) void final_kernel(
    const float* __restrict__ gpre, const float* __restrict__ enr,
    const float* __restrict__ hid, const float* __restrict__ outw,
    const float* __restrict__ outb, float* __restrict__ out)
{
  int b = blockIdx.x, j = threadIdx.x;
  float gt = sigf(gpre[b * 256 + j]);
  float comb = gt * enr[b * 256 + j] + (1.f - gt) * hid[b * 256 + j];
  float v = comb * outw[j];
  float s = blk_sum(v);
  if (j == 0) out[b] = s + outb[0];
}

// ---------------- one-shot weight prep ----------------
// wpk layout: elem = ((((s*4+w)*4+g)*16+k)*64+lane)*8 + j
// row = g*256 + s*64 + w*16 + (lane&15); col = k*32 + (lane>>4)*8 + j
// threads: 524288 + 3*65536 + 131072 + 2*1024 = 854016 = 3336 blocks
__global__ void prep_kernel(
    const float* Wih0, const float* Whh0, const float* Wih1, const float* Whh1,
    const float* bih0, const float* bhh0, const float* bih1, const float* bhh1,
    const float* attn_in_w, const float* attn_out_w, const float* gnn_w,
    const float* gate_w,
    f16* wpk0, f16* wpk1, f16* attninf, f16* attnoutf, f16* gnnwf, f16* gatewf,
    float* bias0, float* bias1)
{
  int idx = blockIdx.x * 256 + threadIdx.x;
  if (idx < 524288) {
    int j = idx & 7, lane = (idx >> 3) & 63, k = (idx >> 9) & 15;
    int g = (idx >> 13) & 3, w = (idx >> 15) & 3, s = (idx >> 17) & 3;
    int row = g * 256 + s * 64 + w * 16 + (lane & 15);
    int col = k * 32 + (lane >> 4) * 8 + j;
    float v0 = col < 256 ? Wih0[(size_t)row * 256 + col] : Whh0[(size_t)row * 256 + col - 256];
    float v1 = col < 256 ? Wih1[(size_t)row * 256 + col] : Whh1[(size_t)row * 256 + col - 256];
    wpk0[idx] = (f16)v0;
    wpk1[idx] = (f16)v1;
    return;
  }
  int i = idx - 524288;
  if (i < 65536) { attninf[i] = (f16)attn_in_w[i]; return; }
  i -= 65536;
  if (i < 65536) { attnoutf[i] = (f16)attn_out_w[i]; return; }
  i -= 65536;
  if (i < 65536) { gnnwf[i] = (f16)gnn_w[i]; return; }
  i -= 65536;
  if (i < 131072) { gatewf[i] = (f16)gate_w[i]; return; }
  i -= 131072;
  if (i < 1024) { bias0[i] = bih0[i] + bhh0[i]; return; }
  i -= 1024;
  if (i < 1024) { bias1[i] = bih1[i] + bhh1[i]; return; }
}

// ---------------- launch ----------------
extern "C" void kernel_launch(void* const* d_in, const int* in_sizes, int n_in,
                              void* d_out, int out_size, void* d_ws, size_t ws_size,
                              hipStream_t stream)
{
  const float* x         = (const float*)d_in[0];
  const int*   sku       = (const int*)  d_in[1];
  const float* adj       = (const float*)d_in[2];
  const float* vsn_emb_w = (const float*)d_in[3];
  const float* vsn_emb_b = (const float*)d_in[4];
  const float* vsn_sel_w = (const float*)d_in[5];
  const float* vsn_sel_b = (const float*)d_in[6];
  const float* Wih0 = (const float*)d_in[7];
  const float* Whh0 = (const float*)d_in[8];
  const float* bih0 = (const float*)d_in[9];
  const float* bhh0 = (const float*)d_in[10];
  const float* Wih1 = (const float*)d_in[11];
  const float* Whh1 = (const float*)d_in[12];
  const float* bih1 = (const float*)d_in[13];
  const float* bhh1 = (const float*)d_in[14];
  const float* attn_in_w  = (const float*)d_in[15];
  const float* attn_in_b  = (const float*)d_in[16];
  const float* attn_out_w = (const float*)d_in[17];
  const float* attn_out_b = (const float*)d_in[18];
  const float* gnn_w  = (const float*)d_in[19];
  const float* gnn_b  = (const float*)d_in[20];
  const float* ln_g   = (const float*)d_in[21];
  const float* ln_b   = (const float*)d_in[22];
  const float* gate_w = (const float*)d_in[23];
  const float* gate_b = (const float*)d_in[24];
  const float* out_w  = (const float*)d_in[25];
  const float* out_b  = (const float*)d_in[26];
  (void)in_sizes; (void)n_in; (void)out_size; (void)ws_size;

  const size_t HBYTES = (size_t)B_ * T_ * H_ * 2;   // 67 MB per h buffer

  char* wsb = (char*)d_ws;
  size_t off = 0;
  auto alloc = [&](size_t bytes) -> void* {
    void* p = wsb + off;
    off += (bytes + 255) & ~(size_t)255;
    return p;
  };
  // persistent
  f16* hA      = (f16*)alloc(HBYTES);   // vsn out / lstm0 in; lstm1 out (final h)
  size_t off_hB = off;
  f16* hB      = (f16*)alloc(HBYTES);   // lstm0 out / lstm1 in; dead after lstm1
  f16* wpk0    = (f16*)alloc((size_t)1024 * 512 * 2);
  f16* wpk1    = (f16*)alloc((size_t)1024 * 512 * 2);
  f16* attninf = (f16*)alloc((size_t)256 * 256 * 2);
  f16* attnoutf= (f16*)alloc((size_t)256 * 256 * 2);
  f16* gnnwf   = (f16*)alloc((size_t)256 * 256 * 2);
  f16* gatewf  = (f16*)alloc((size_t)256 * 512 * 2);
  float* bias0 = (float*)alloc(1024 * 4);
  float* bias1 = (float*)alloc(1024 * 4);
  // tail buffers alias the hB region (hB is dead once lstm1 completes; all
  // tail buffers are first written after lstm1). wb (vsn scratch) also lives
  // there and is dead before the 0xFF poison of hB (stream-ordered after vsn).
  off = off_hB;
  float* wb    = (float*)alloc((size_t)B_ * T_ * 18 * 4);   // 9.4 MB, vsn only
  float* qbuf  = (float*)alloc((size_t)B_ * 256 * 4);
  float* qk    = (float*)alloc((size_t)B_ * 4 * 256 * 4);
  float* hbar  = (float*)alloc((size_t)B_ * 4 * 256 * 4);
  f16* aob     = (f16*)alloc((size_t)B_ * 256 * 2);
  float* hidden32 = (float*)alloc((size_t)B_ * 256 * 4);
  f16* hidcat  = (f16*)alloc((size_t)B_ * 512 * 2);
  f16* hT      = (f16*)alloc((size_t)256 * B_ * 2);
  f16* adjn    = (f16*)alloc((size_t)B_ * B_ * 2);
  f16* aggf    = (f16*)alloc((size_t)B_ * 256 * 2);
  float* gnnpre= (float*)alloc((size_t)B_ * 256 * 4);
  float* enr32 = (float*)alloc((size_t)B_ * 256 * 4);
  float* gatepre=(float*)alloc((size_t)B_ * 256 * 4);
  // (total tail ~27 MB < 67 MB hB region)

  prep_kernel<<<3336, 256, 0, stream>>>(
      Wih0, Whh0, Wih1, Whh1, bih0, bhh0, bih1, bhh1,
      attn_in_w, attn_out_w, gnn_w, gate_w,
      wpk0, wpk1, attninf, attnoutf, gnnwf, gatewf, bias0, bias1);

  // 1) VSN -> hA  (wb scratch lives in the hB region; poison comes after)
  vsn_w_kernel<<<512, 256, 0, stream>>>(x, vsn_sel_w, vsn_sel_b, wb);
  vsn_h_kernel<<<1024, 256, 0, stream>>>(wb, vsn_emb_w, vsn_emb_b, hA);
  // 2) LSTM layers, out-of-place, poison-validate + 2-group interleave
  hipMemsetAsync(hB, 0xFF, HBYTES, stream);           // poison lstm0 out
  lstm2<<<128, 256, 0, stream>>>(hA, hB, wpk0, bias0);
  hipMemsetAsync(hA, 0xFF, HBYTES, stream);           // poison lstm1 out
  lstm2<<<128, 256, 0, stream>>>(hB, hA, wpk1, bias1);

  // 3) q at t=T-1
  dim3 gS(B_ / 128, 256 / 128);
  gemm_f16<<<gS, 256, 0, stream>>>(hA + (size_t)(T_ - 1) * 256, T_ * 256, attninf, 256,
                                   attn_in_b, nullptr, 0, qbuf, 256, B_, 256, 256);
  // 4) attention folded into h-space
  qk_kernel<<<B_, 256, 0, stream>>>(qbuf, attn_in_w, qk);
  attnpool_kernel<<<B_, 256, 0, stream>>>(hA, qk, hbar);
  vproj_kernel<<<B_, 256, 0, stream>>>(hbar, attn_in_w, attn_in_b, aob);
  // 5) hidden
  gemm_f16<<<gS, 256, 0, stream>>>(aob, 256, attnoutf, 256, attn_out_b,
                                   hidcat, 512, hidden32, 256, B_, 256, 256);
  // 6) GNN
  deg_adjn_kernel<<<B_, 256, 0, stream>>>(adj, sku, adjn);
  transpose_kernel<<<B_, 256, 0, stream>>>(hidden32, hT);
  gemm_f16<<<gS, 256, 0, stream>>>(adjn, 1024, hT, 1024, nullptr,
                                   aggf, 256, nullptr, 0, B_, 256, 1024);
  gemm_f16<<<gS, 256, 0, stream>>>(aggf, 256, gnnwf, 256, gnn_b,
                                   nullptr, 0, gnnpre, 256, B_, 256, 256);
  gelu_ln_kernel<<<B_, 256, 0, stream>>>(gnnpre, ln_g, ln_b, enr32, hidcat);
  // 7) gate + output
  gemm_f16<<<gS, 256, 0, stream>>>(hidcat, 512, gatewf, 512, gate_b,
                                   nullptr, 0, gatepre, 256, B_, 256, 512);
  final_kernel<<<B_, 256, 0, stream>>>(gatepre, enr32, hidden32, out_w, out_b, (float*)d_out);
}

// Round 5
// 1011.660 us; speedup vs baseline: 1.8301x; 1.8301x over previous
//
#include <hip/hip_runtime.h>
#include <hip/hip_fp16.h>

typedef _Float16 f16;
typedef _Float16 f16x8 __attribute__((ext_vector_type(8)));
typedef _Float16 f16x4 __attribute__((ext_vector_type(4)));
typedef float f32x4 __attribute__((ext_vector_type(4)));

#define B_ 1024
#define T_ 128
#define F_ 9
#define H_ 256
#define P_ 2048

#define AL(p) __hip_atomic_load((p), __ATOMIC_RELAXED, __HIP_MEMORY_SCOPE_AGENT)
#define AS(p, v) __hip_atomic_store((p), (v), __ATOMIC_RELAXED, __HIP_MEMORY_SCOPE_AGENT)

// ---------------- helpers ----------------
__device__ __forceinline__ float sigf(float x) { return 1.f / (1.f + __expf(-x)); }
__device__ __forceinline__ float tanh_(float x) {
  float a = fminf(fabsf(x), 12.f);
  float e = __expf(2.f * a);
  float r = 1.f - 2.f / (e + 1.f);
  return copysignf(r, x);
}

__device__ __forceinline__ f16x8 aload16(const f16* p) {
  union { unsigned long long u[2]; f16x8 v; } r;
  r.u[0] = AL((const unsigned long long*)p);
  r.u[1] = AL((const unsigned long long*)p + 1);
  return r.v;
}

__device__ __forceinline__ float blk_sum(float v) {
  __shared__ float sh[8];
  int lane = threadIdx.x & 63, w = threadIdx.x >> 6;
  int nw = blockDim.x >> 6;
#pragma unroll
  for (int o = 32; o > 0; o >>= 1) v += __shfl_xor(v, o, 64);
  __syncthreads();
  if (lane == 0) sh[w] = v;
  __syncthreads();
  float t = 0.f;
  for (int i = 0; i < nw; i++) t += sh[i];
  return t;
}

// ---------------- generic fp16 MFMA GEMM ----------------
__global__ __launch_bounds__(256) void gemm_f16(
    const f16* __restrict__ A, int lda,
    const f16* __restrict__ Bt, int ldb,
    const float* __restrict__ bias,
    f16* __restrict__ o16, int ldo16,
    float* __restrict__ o32, int ldo32,
    int M, int N, int K)
{
  __shared__ __align__(16) f16 As[128][40];
  __shared__ __align__(16) f16 Bs[128][40];
  const int tid = threadIdx.x;
  const int lane = tid & 63, wave = tid >> 6;
  const int wr = (wave >> 1) * 64, wc = (wave & 1) * 64;
  const int q = lane >> 4, l15 = lane & 15;
  const int bm = blockIdx.x * 128, bn = blockIdx.y * 128;

  f32x4 acc[4][4];
#pragma unroll
  for (int i = 0; i < 4; i++)
#pragma unroll
    for (int j = 0; j < 4; j++) acc[i][j] = (f32x4){0.f, 0.f, 0.f, 0.f};

  for (int k0 = 0; k0 < K; k0 += 32) {
#pragma unroll
    for (int c = 0; c < 2; ++c) {
      int ch = tid + c * 256;
      int row = ch >> 2, kh = (ch & 3) * 8;
      *(f16x8*)&As[row][kh] = *(const f16x8*)&A[(size_t)(bm + row) * lda + k0 + kh];
      *(f16x8*)&Bs[row][kh] = *(const f16x8*)&Bt[(size_t)(bn + row) * ldb + k0 + kh];
    }
    __syncthreads();
    f16x8 af[4], bf[4];
#pragma unroll
    for (int tm = 0; tm < 4; tm++) af[tm] = *(const f16x8*)&As[wr + tm * 16 + l15][q * 8];
#pragma unroll
    for (int tn = 0; tn < 4; tn++) bf[tn] = *(const f16x8*)&Bs[wc + tn * 16 + l15][q * 8];
#pragma unroll
    for (int tm = 0; tm < 4; tm++)
#pragma unroll
      for (int tn = 0; tn < 4; tn++)
        acc[tm][tn] = __builtin_amdgcn_mfma_f32_16x16x32_f16(af[tm], bf[tn], acc[tm][tn], 0, 0, 0);
    __syncthreads();
  }
#pragma unroll
  for (int tm = 0; tm < 4; tm++) {
#pragma unroll
    for (int tn = 0; tn < 4; tn++) {
      int colg = bn + wc + tn * 16 + l15;
      float bv = bias ? bias[colg] : 0.f;
#pragma unroll
      for (int r = 0; r < 4; r++) {
        int rowg = bm + wr + tm * 16 + q * 4 + r;
        float v = acc[tm][tn][r] + bv;
        if (o32) o32[(size_t)rowg * ldo32 + colg] = v;
        if (o16) o16[(size_t)rowg * ldo16 + colg] = (f16)v;
      }
    }
  }
}

// ---------------- LSTM v6: both layers pipelined, v2 counter protocol ------
// R4 lesson: program-order interleaving inside one block cannot hide a
// latency that ends in a blocking poll. What hides waits on CDNA is the
// SIMD scheduler switching to another RESIDENT wave -> put the independent
// work in a different block on the same CU. The independent work: LAYER 1,
// whose step t needs only layer 0's h0_t. Pipeline: LSTM wall-time becomes
// (T+lag)*tau instead of 2T*tau.
//
// Geometry: 32 rows/group (2 MFMA M-tiles; weights are per-column-slice so
// register cost is unchanged, acc doubles to 32 VGPR). 32 groups x 4 slices
// = 128 blocks/layer; both layers = 256 blocks = 1/CU, all co-resident
// (same assumption R1's grid already relied on).
//
// Protocol: R1's proven v2 counter scheme verbatim, in place on hio, per
// layer (cnt0/cnt1; signal step t only after h stores drained AND x_{t+1}
// prefetch completed -> phase-A (cnt>=4t+4) makes slot t+1 clobber-safe).
// Layer-1 addition: phase-A also waits cnt0[g] >= min(4t+12, 516), i.e.
// layer 0 finished step t+1. This one condition covers all cross-layer
// hazards: (a) h0_t, h0_{t+1} written+drained (x consume/prefetch);
// (b) all layer-0 readers of slot t are done (its stage-read of slot t
// happens during its step t+1, before that signal) -> layer-1's in-place
// h1_t write cannot clobber h0_t early. Layer-1's own v2 invariant
// protects h0 slots from its peers exactly as x was protected in R1.
// Layer 0 never waits on layer 1 -> no deadlock cycle; capped polls bail.
// Layer-1 x loads use agent-scope atomics (h0 was written sc1 past the
// per-XCD L2s; plain loads could hit stale cache lines).
__global__ __launch_bounds__(256, 1) void lstm_pipe(
    f16* __restrict__ hio,
    const f16* __restrict__ wpk0, const f16* __restrict__ wpk1,
    const float* __restrict__ b0, const float* __restrict__ b1,
    int* __restrict__ cnt0, int* __restrict__ cnt1)
{
  __shared__ __align__(16) f16 apf[2][16][64][8];   // A-frags per M-tile, 32 KB
  __shared__ __align__(16) f16 htile[32][64];       // 4 KB
  const int tid = threadIdx.x;
  const int lane = tid & 63, w = tid >> 6;          // wave 0..3
  const int q = lane >> 4, l15 = lane & 15;
  const int layer = blockIdx.x >> 7;                // 0..127 -> L0, 128..255 -> L1
  const int lbid = blockIdx.x & 127;
  const int grp = lbid & 31, s = lbid >> 5;         // 32 groups x 4 col-slices
  const int m0 = grp * 32;
  const f16* wpk = layer ? wpk1 : wpk0;
  const float* bias = layer ? b1 : b0;
  int* mycnt = (layer ? cnt1 : cnt0) + grp * 64;
  int* xcnt  = cnt0 + grp * 64;                     // layer 1 watches layer 0

  // ---- weight slice into registers: 64 x f16x8 = 256 regs/lane ----
  f16x8 bf[4][16];
  {
    const f16* wbase = wpk + (((size_t)(s * 4 + w) * 4) * 16) * 512 + lane * 8;
#pragma unroll
    for (int g = 0; g < 4; g++)
#pragma unroll
      for (int k = 0; k < 16; k++)
        bf[g][k] = *(const f16x8*)(wbase + (size_t)(g * 16 + k) * 512);
  }
  float bv[4];
#pragma unroll
  for (int g = 0; g < 4; g++) bv[g] = bias[g * 256 + s * 64 + w * 16 + l15];

  // staging geometry (per M-tile): thread owns apf[mt][k][lane] for
  // k in {w,w+4} (x halves) and {8+w,12+w} (h halves);
  // element (row=lane&15, col=k*32+(lane>>4)*8+j).
  const int srow = lane & 15, scb = lane >> 4;
  size_t rb[2];
  rb[0] = ((size_t)(m0 + srow) * T_) * 256 + scb * 8;
  rb[1] = ((size_t)(m0 + 16 + srow) * T_) * 256 + scb * 8;

  const f16x8 zv = {(f16)0, (f16)0, (f16)0, (f16)0, (f16)0, (f16)0, (f16)0, (f16)0};
  const int xcap = 4 + 4 * T_;     // cnt0 terminal value (516)

  // pre-loop: layer 1 must wait for h0_0 before reading its x_0
  if (layer) {
    if (tid == 0) {
      int it = 0;
      while (AL(xcnt) < 8) {
        __builtin_amdgcn_s_sleep(1);
        if (++it > (1 << 22)) break;
      }
    }
    __syncthreads();
  }
  f16x8 xr[2][2];
#pragma unroll
  for (int mt = 0; mt < 2; mt++) {
    if (layer) {
      xr[mt][0] = aload16(&hio[rb[mt] + (size_t)w * 32]);
      xr[mt][1] = aload16(&hio[rb[mt] + (size_t)(w + 4) * 32]);
    } else {
      xr[mt][0] = *(const f16x8*)&hio[rb[mt] + (size_t)w * 32];
      xr[mt][1] = *(const f16x8*)&hio[rb[mt] + (size_t)(w + 4) * 32];
    }
  }
  float cst[2][4] = {{0.f, 0.f, 0.f, 0.f}, {0.f, 0.f, 0.f, 0.f}};

  __syncthreads();                   // drains all lanes' x_0 loads
  if (tid == 0)                      // initial signal: x_0 prefetched
    __hip_atomic_fetch_add(mycnt, 1, __ATOMIC_RELAXED, __HIP_MEMORY_SCOPE_AGENT);

  for (int t = 0; t < T_; ++t) {
    // phase A: own group done with step t-1; (L1) layer 0 done with step t+1
    if (tid == 0) {
      int needO = 4 * t + 4;
      int needX = 0;
      if (layer) { needX = 4 * t + 12; if (needX > xcap) needX = xcap; }
      int it = 0;
      for (;;) {
        int a = AL(mycnt);
        int b = needX ? AL(xcnt) : 0;
        if (a >= needO && b >= needX) break;
        __builtin_amdgcn_s_sleep(1);
        if (++it > (1 << 22)) break;   // bailout: wrong answer beats a hang
      }
    }
    __syncthreads();
    // stage x_t (prefetch regs) and h_{t-1} (peers' sc1 writes)
#pragma unroll
    for (int mt = 0; mt < 2; mt++) {
      *(f16x8*)&apf[mt][w][lane][0]     = xr[mt][0];
      *(f16x8*)&apf[mt][w + 4][lane][0] = xr[mt][1];
      f16x8 h0 = zv, h1 = zv;
      if (t > 0) {
        h0 = aload16(&hio[rb[mt] + (size_t)(t - 1) * 256 + (size_t)w * 32]);
        h1 = aload16(&hio[rb[mt] + (size_t)(t - 1) * 256 + (size_t)(w + 4) * 32]);
      }
      *(f16x8*)&apf[mt][8 + w][lane][0]  = h0;
      *(f16x8*)&apf[mt][12 + w][lane][0] = h1;
    }
    __syncthreads();

    // ---- compute: 128 MFMAs (2 M-tiles), B-operands in registers ----
    f32x4 acc[2][4];
#pragma unroll
    for (int mt = 0; mt < 2; mt++)
#pragma unroll
      for (int g = 0; g < 4; g++) acc[mt][g] = (f32x4){0.f, 0.f, 0.f, 0.f};
#pragma unroll
    for (int k = 0; k < 16; k++) {
      f16x8 a0 = *(const f16x8*)&apf[0][k][lane][0];
      f16x8 a1 = *(const f16x8*)&apf[1][k][lane][0];
#pragma unroll
      for (int g = 0; g < 4; g++) {
        acc[0][g] = __builtin_amdgcn_mfma_f32_16x16x32_f16(a0, bf[g][k], acc[0][g], 0, 0, 0);
        acc[1][g] = __builtin_amdgcn_mfma_f32_16x16x32_f16(a1, bf[g][k], acc[1][g], 0, 0, 0);
      }
    }
    // prefetch x_{t+1}; for L1 this is h0_{t+1}, guaranteed by phase-A xcnt
    if (t + 1 < T_) {
#pragma unroll
      for (int mt = 0; mt < 2; mt++) {
        if (layer) {
          xr[mt][0] = aload16(&hio[rb[mt] + (size_t)(t + 1) * 256 + (size_t)w * 32]);
          xr[mt][1] = aload16(&hio[rb[mt] + (size_t)(t + 1) * 256 + (size_t)(w + 4) * 32]);
        } else {
          xr[mt][0] = *(const f16x8*)&hio[rb[mt] + (size_t)(t + 1) * 256 + (size_t)w * 32];
          xr[mt][1] = *(const f16x8*)&hio[rb[mt] + (size_t)(t + 1) * 256 + (size_t)(w + 4) * 32];
        }
      }
    }
    // gate math (lane: rows mt*16 + q*4+r, col s*64+w*16+l15)
    f16 hn[2][4];
#pragma unroll
    for (int mt = 0; mt < 2; mt++)
#pragma unroll
      for (int r = 0; r < 4; r++) {
        float ip = acc[mt][0][r] + bv[0];
        float fp = acc[mt][1][r] + bv[1];
        float gp = acc[mt][2][r] + bv[2];
        float op = acc[mt][3][r] + bv[3];
        float cn = sigf(fp) * cst[mt][r] + sigf(ip) * tanh_(gp);
        cst[mt][r] = cn;
        hn[mt][r] = (f16)(sigf(op) * tanh_(cn));
      }
    __syncthreads();                 // apf reads done; htile reusable
#pragma unroll
    for (int mt = 0; mt < 2; mt++)
#pragma unroll
      for (int r = 0; r < 4; r++)
        htile[mt * 16 + q * 4 + r][w * 16 + l15] = hn[mt][r];
    __syncthreads();                 // htile ready; drains xr prefetch loads
    {                                // write h_t over slot t (16B/thread)
      int row = tid >> 3, c8 = (tid & 7) * 8;
      union { unsigned long long u[2]; f16x8 v; } uh;
      uh.v = *(const f16x8*)&htile[row][c8];
      unsigned long long* dst =
          (unsigned long long*)&hio[((size_t)(m0 + row) * T_ + t) * 256 + s * 64 + c8];
      AS(dst, uh.u[0]);
      AS(dst + 1, uh.u[1]);
    }
    __syncthreads();                 // drains h stores from all lanes
    if (tid == 0)
      __hip_atomic_fetch_add(mycnt, 1, __ATOMIC_RELAXED, __HIP_MEMORY_SCOPE_AGENT);
  }
}

// ---------------- VSN, two-phase ----------------
__global__ __launch_bounds__(256) void vsn_w_kernel(
    const float* __restrict__ x, const float* __restrict__ selw,
    const float* __restrict__ selb, float* __restrict__ wb)
{
  int pos = blockIdx.x * 256 + threadIdx.x;
  const float* xr = x + (size_t)pos * F_;
  float xv[F_];
#pragma unroll
  for (int f = 0; f < F_; f++) xv[f] = xr[f];
  float wv[F_]; float mx = -1e30f;
#pragma unroll
  for (int f = 0; f < F_; f++) {
    float s = selb[f];
#pragma unroll
    for (int f2 = 0; f2 < F_; f2++) s += xv[f2] * selw[f * F_ + f2];
    wv[f] = s; mx = fmaxf(mx, s);
  }
  float se = 0.f;
#pragma unroll
  for (int f = 0; f < F_; f++) { wv[f] = __expf(wv[f] - mx); se += wv[f]; }
  float inv = 1.f / se;
  float* o = wb + (size_t)pos * 18;
#pragma unroll
  for (int f = 0; f < F_; f++) {
    float wt = wv[f] * inv;
    o[f] = wt; o[9 + f] = wt * xv[f];
  }
}

__global__ __launch_bounds__(256) void vsn_h_kernel(
    const float* __restrict__ wb, const float* __restrict__ embw,
    const float* __restrict__ embb, f16* __restrict__ hout)
{
  int j = threadIdx.x;
  float ew[F_], eb[F_];
#pragma unroll
  for (int f = 0; f < F_; f++) { ew[f] = embw[f * H_ + j]; eb[f] = embb[f * H_ + j]; }
  for (int i = 0; i < 128; i++) {
    size_t pos = blockIdx.x + (size_t)i * 1024;
    const float* w = wb + pos * 18;
    float h = 0.f;
#pragma unroll
    for (int f = 0; f < F_; f++) h += w[9 + f] * ew[f] + w[f] * eb[f];
    hout[pos * H_ + j] = (f16)h;
  }
}

// ---------------- attention in h-space ----------------
__global__ __launch_bounds__(256) void qk_kernel(
    const float* __restrict__ qbuf, const float* __restrict__ attn_in_w,
    float* __restrict__ qk)
{
  __shared__ float qs[256];
  int b = blockIdx.x, j = threadIdx.x;
  qs[j] = qbuf[(size_t)b * 256 + j];
  __syncthreads();
#pragma unroll
  for (int h = 0; h < 4; h++) {
    float acc = 0.f;
    for (int d = 0; d < 64; d++)
      acc += qs[h * 64 + d] * attn_in_w[(size_t)(256 + h * 64 + d) * 256 + j];
    qk[((size_t)b * 4 + h) * 256 + j] = acc * 0.125f;
  }
}

__global__ __launch_bounds__(256) void attnpool_kernel(
    const f16* __restrict__ hseq, const float* __restrict__ qk,
    float* __restrict__ hbar)
{
  __shared__ __align__(16) f16 hs[T_][264];
  __shared__ float qks[4][256];
  __shared__ float ps[4][T_];
  int b = blockIdx.x, tid = threadIdx.x;
  for (int i = tid; i < T_ * 32; i += 256) {
    int row = i >> 5, cc = (i & 31) * 8;
    *(f16x8*)&hs[row][cc] = *(const f16x8*)&hseq[((size_t)b * T_ + row) * 256 + cc];
  }
  for (int i = tid; i < 1024; i += 256) qks[i >> 8][i & 255] = qk[(size_t)b * 1024 + i];
  __syncthreads();
  if (tid < T_) {
    float s[4] = {0.f, 0.f, 0.f, 0.f};
    for (int cc = 0; cc < 32; cc++) {
      f16x8 v = *(const f16x8*)&hs[tid][cc * 8];
#pragma unroll
      for (int h = 0; h < 4; h++) {
        float a = 0.f;
#pragma unroll
        for (int j = 0; j < 8; j++) a += qks[h][cc * 8 + j] * (float)v[j];
        s[h] += a;
      }
    }
#pragma unroll
    for (int h = 0; h < 4; h++) ps[h][tid] = s[h];
  }
  __syncthreads();
  {
    int w = tid >> 6, l = tid & 63;
    float a = ps[w][l], bb = ps[w][l + 64];
    float m = fmaxf(a, bb);
#pragma unroll
    for (int o = 32; o > 0; o >>= 1) m = fmaxf(m, __shfl_xor(m, o, 64));
    float e0 = __expf(a - m), e1 = __expf(bb - m);
    float se = e0 + e1;
#pragma unroll
    for (int o = 32; o > 0; o >>= 1) se += __shfl_xor(se, o, 64);
    float inv = 1.f / se;
    ps[w][l] = e0 * inv; ps[w][l + 64] = e1 * inv;
  }
  __syncthreads();
  int j = tid;
  float acc[4] = {0.f, 0.f, 0.f, 0.f};
  for (int t = 0; t < T_; t++) {
    float hv = (float)hs[t][j];
#pragma unroll
    for (int h = 0; h < 4; h++) acc[h] += ps[h][t] * hv;
  }
#pragma unroll
  for (int h = 0; h < 4; h++) hbar[((size_t)b * 4 + h) * 256 + j] = acc[h];
}

__global__ __launch_bounds__(256) void vproj_kernel(
    const float* __restrict__ hbar, const float* __restrict__ attn_in_w,
    const float* __restrict__ attn_in_b, f16* __restrict__ aob)
{
  __shared__ float hb[4][256];
  int b = blockIdx.x, tid = threadIdx.x;
  for (int i = tid; i < 1024; i += 256) hb[i >> 8][i & 255] = hbar[(size_t)b * 1024 + i];
  __syncthreads();
  int d = tid, h = d >> 6;
  const float4* wr = (const float4*)(attn_in_w + (size_t)(512 + d) * 256);
  float acc = 0.f;
  for (int cc = 0; cc < 64; cc++) {
    float4 w4 = wr[cc];
    acc += w4.x * hb[h][cc * 4] + w4.y * hb[h][cc * 4 + 1]
         + w4.z * hb[h][cc * 4 + 2] + w4.w * hb[h][cc * 4 + 3];
  }
  aob[(size_t)b * 256 + d] = (f16)(acc + attn_in_b[512 + d]);
}

// ---------------- GNN prep ----------------
__global__ __launch_bounds__(256) void deg_adjn_kernel(
    const float* __restrict__ adj, const int* __restrict__ sku,
    f16* __restrict__ adjn)
{
  int bp = blockIdx.x;
  int p = sku[bp];
  int tid = threadIdx.x;
  float s = 0.f;
  for (int j = tid; j < P_; j += 256) s += adj[(size_t)p * P_ + j];
  float tot = blk_sum(s);
  float inv = 1.f / fmaxf(tot, 1e-6f);
  for (int b = tid; b < B_; b += 256)
    adjn[(size_t)bp * B_ + b] = (f16)(adj[(size_t)p * P_ + sku[b]] * inv);
}

__global__ void transpose_kernel(const float* __restrict__ hid, f16* __restrict__ hT)
{
  int i = blockIdx.x * 256 + threadIdx.x;
  int b = i >> 8, j = i & 255;
  hT[(size_t)j * B_ + b] = (f16)hid[i];
}

__global__ __launch_bounds__(256) void gelu_ln_kernel(
    const float* __restrict__ pre, const float* __restrict__ lg,
    const float* __restrict__ lb, float* __restrict__ enr,
    f16* __restrict__ hidcat)
{
  int row = blockIdx.x, j = threadIdx.x;
  float xv = pre[row * 256 + j];
  float ge = 0.5f * xv * (1.f + erff(xv * 0.70710678118654752f));
  float mu = blk_sum(ge) * (1.f / 256.f);
  float d = ge - mu;
  float var = blk_sum(d * d) * (1.f / 256.f);
  float y = d * rsqrtf(var + 1e-5f) * lg[j] + lb[j];
  enr[row * 256 + j] = y;
  hidcat[row * 512 + 256 + j] = (f16)y;
}

__global__ __launch_bounds__(256) void final_kernel(
    const float* __restrict__ gpre, const float* __restrict__ enr,
    const float* __restrict__ hid, const float* __restrict__ outw,
    const float* __restrict__ outb, float* __restrict__ out)
{
  int b = blockIdx.x, j = threadIdx.x;
  float gt = sigf(gpre[b * 256 + j]);
  float comb = gt * enr[b * 256 + j] + (1.f - gt) * hid[b * 256 + j];
  float v = comb * outw[j];
  float s = blk_sum(v);
  if (j == 0) out[b] = s + outb[0];
}

// ---------------- one-shot weight prep ----------------
// wpk layout: elem = ((((s*4+w)*4+g)*16+k)*64+lane)*8 + j
// row = g*256 + s*64 + w*16 + (lane&15); col = k*32 + (lane>>4)*8 + j
// threads: 524288 + 3*65536 + 131072 + 2*1024 = 854016 = 3336 blocks
__global__ void prep_kernel(
    const float* Wih0, const float* Whh0, const float* Wih1, const float* Whh1,
    const float* bih0, const float* bhh0, const float* bih1, const float* bhh1,
    const float* attn_in_w, const float* attn_out_w, const float* gnn_w,
    const float* gate_w,
    f16* wpk0, f16* wpk1, f16* attninf, f16* attnoutf, f16* gnnwf, f16* gatewf,
    float* bias0, float* bias1)
{
  int idx = blockIdx.x * 256 + threadIdx.x;
  if (idx < 524288) {
    int j = idx & 7, lane = (idx >> 3) & 63, k = (idx >> 9) & 15;
    int g = (idx >> 13) & 3, w = (idx >> 15) & 3, s = (idx >> 17) & 3;
    int row = g * 256 + s * 64 + w * 16 + (lane & 15);
    int col = k * 32 + (lane >> 4) * 8 + j;
    float v0 = col < 256 ? Wih0[(size_t)row * 256 + col] : Whh0[(size_t)row * 256 + col - 256];
    float v1 = col < 256 ? Wih1[(size_t)row * 256 + col] : Whh1[(size_t)row * 256 + col - 256];
    wpk0[idx] = (f16)v0;
    wpk1[idx] = (f16)v1;
    return;
  }
  int i = idx - 524288;
  if (i < 65536) { attninf[i] = (f16)attn_in_w[i]; return; }
  i -= 65536;
  if (i < 65536) { attnoutf[i] = (f16)attn_out_w[i]; return; }
  i -= 65536;
  if (i < 65536) { gnnwf[i] = (f16)gnn_w[i]; return; }
  i -= 65536;
  if (i < 131072) { gatewf[i] = (f16)gate_w[i]; return; }
  i -= 131072;
  if (i < 1024) { bias0[i] = bih0[i] + bhh0[i]; return; }
  i -= 1024;
  if (i < 1024) { bias1[i] = bih1[i] + bhh1[i]; return; }
}

// ---------------- launch ----------------
extern "C" void kernel_launch(void* const* d_in, const int* in_sizes, int n_in,
                              void* d_out, int out_size, void* d_ws, size_t ws_size,
                              hipStream_t stream)
{
  const float* x         = (const float*)d_in[0];
  const int*   sku       = (const int*)  d_in[1];
  const float* adj       = (const float*)d_in[2];
  const float* vsn_emb_w = (const float*)d_in[3];
  const float* vsn_emb_b = (const float*)d_in[4];
  const float* vsn_sel_w = (const float*)d_in[5];
  const float* vsn_sel_b = (const float*)d_in[6];
  const float* Wih0 = (const float*)d_in[7];
  const float* Whh0 = (const float*)d_in[8];
  const float* bih0 = (const float*)d_in[9];
  const float* bhh0 = (const float*)d_in[10];
  const float* Wih1 = (const float*)d_in[11];
  const float* Whh1 = (const float*)d_in[12];
  const float* bih1 = (const float*)d_in[13];
  const float* bhh1 = (const float*)d_in[14];
  const float* attn_in_w  = (const float*)d_in[15];
  const float* attn_in_b  = (const float*)d_in[16];
  const float* attn_out_w = (const float*)d_in[17];
  const float* attn_out_b = (const float*)d_in[18];
  const float* gnn_w  = (const float*)d_in[19];
  const float* gnn_b  = (const float*)d_in[20];
  const float* ln_g   = (const float*)d_in[21];
  const float* ln_b   = (const float*)d_in[22];
  const float* gate_w = (const float*)d_in[23];
  const float* gate_b = (const float*)d_in[24];
  const float* out_w  = (const float*)d_in[25];
  const float* out_b  = (const float*)d_in[26];
  (void)in_sizes; (void)n_in; (void)out_size; (void)ws_size;

  char* wsb = (char*)d_ws;
  size_t off = 0;
  auto alloc = [&](size_t bytes) -> void* {
    void* p = wsb + off;
    off += (bytes + 255) & ~(size_t)255;
    return p;
  };
  // persistent
  f16* hA      = (f16*)alloc((size_t)B_ * T_ * H_ * 2);   // 67 MB, in-place pipeline
  f16* wpk0    = (f16*)alloc((size_t)1024 * 512 * 2);
  f16* wpk1    = (f16*)alloc((size_t)1024 * 512 * 2);
  f16* attninf = (f16*)alloc((size_t)256 * 256 * 2);
  f16* attnoutf= (f16*)alloc((size_t)256 * 256 * 2);
  f16* gnnwf   = (f16*)alloc((size_t)256 * 256 * 2);
  f16* gatewf  = (f16*)alloc((size_t)256 * 512 * 2);
  float* bias0 = (float*)alloc(1024 * 4);
  float* bias1 = (float*)alloc(1024 * 4);
  int* cnt0    = (int*)alloc(32 * 64 * 4);   // padded: 1 counter / 256B
  int* cnt1    = (int*)alloc(32 * 64 * 4);
  size_t off_tail = off;            // region below reused: wb aliases post-LSTM bufs
  float* qbuf  = (float*)alloc((size_t)B_ * 256 * 4);
  float* qk    = (float*)alloc((size_t)B_ * 4 * 256 * 4);
  float* hbar  = (float*)alloc((size_t)B_ * 4 * 256 * 4);
  f16* aob     = (f16*)alloc((size_t)B_ * 256 * 2);
  float* hidden32 = (float*)alloc((size_t)B_ * 256 * 4);
  f16* hidcat  = (f16*)alloc((size_t)B_ * 512 * 2);
  f16* hT      = (f16*)alloc((size_t)256 * B_ * 2);
  f16* adjn    = (f16*)alloc((size_t)B_ * B_ * 2);
  f16* aggf    = (f16*)alloc((size_t)B_ * 256 * 2);
  float* gnnpre= (float*)alloc((size_t)B_ * 256 * 4);
  float* enr32 = (float*)alloc((size_t)B_ * 256 * 4);
  float* gatepre=(float*)alloc((size_t)B_ * 256 * 4);
  float* wb    = (float*)(wsb + off_tail);  // 9.4 MB, dead before qbuf is written

  // zero the group counters (ws is re-poisoned 0xAA before every launch)
  hipMemsetAsync(cnt0, 0, 2 * 32 * 64 * 4, stream);

  prep_kernel<<<3336, 256, 0, stream>>>(
      Wih0, Whh0, Wih1, Whh1, bih0, bhh0, bih1, bhh1,
      attn_in_w, attn_out_w, gnn_w, gate_w,
      wpk0, wpk1, attninf, attnoutf, gnnwf, gatewf, bias0, bias1);

  // 1) VSN -> hA
  vsn_w_kernel<<<512, 256, 0, stream>>>(x, vsn_sel_w, vsn_sel_b, wb);
  vsn_h_kernel<<<1024, 256, 0, stream>>>(wb, vsn_emb_w, vsn_emb_b, hA);
  // 2) both LSTM layers pipelined in ONE kernel, in place on hA
  lstm_pipe<<<256, 256, 0, stream>>>(hA, wpk0, wpk1, bias0, bias1, cnt0, cnt1);

  // 3) q at t=T-1
  dim3 gS(B_ / 128, 256 / 128);
  gemm_f16<<<gS, 256, 0, stream>>>(hA + (size_t)(T_ - 1) * 256, T_ * 256, attninf, 256,
                                   attn_in_b, nullptr, 0, qbuf, 256, B_, 256, 256);
  // 4) attention folded into h-space
  qk_kernel<<<B_, 256, 0, stream>>>(qbuf, attn_in_w, qk);
  attnpool_kernel<<<B_, 256, 0, stream>>>(hA, qk, hbar);
  vproj_kernel<<<B_, 256, 0, stream>>>(hbar, attn_in_w, attn_in_b, aob);
  // 5) hidden
  gemm_f16<<<gS, 256, 0, stream>>>(aob, 256, attnoutf, 256, attn_out_b,
                                   hidcat, 512, hidden32, 256, B_, 256, 256);
  // 6) GNN
  deg_adjn_kernel<<<B_, 256, 0, stream>>>(adj, sku, adjn);
  transpose_kernel<<<B_, 256, 0, stream>>>(hidden32, hT);
  gemm_f16<<<gS, 256, 0, stream>>>(adjn, 1024, hT, 1024, nullptr,
                                   aggf, 256, nullptr, 0, B_, 256, 1024);
  gemm_f16<<<gS, 256, 0, stream>>>(aggf, 256, gnnwf, 256, gnn_b,
                                   nullptr, 0, gnnpre, 256, B_, 256, 256);
  gelu_ln_kernel<<<B_, 256, 0, stream>>>(gnnpre, ln_g, ln_b, enr32, hidcat);
  // 7) gate + output
  gemm_f16<<<gS, 256, 0, stream>>>(hidcat, 512, gatewf, 512, gate_b,
                                   nullptr, 0, gatepre, 256, B_, 256, 512);
  final_kernel<<<B_, 256, 0, stream>>>(gatepre, enr32, hidden32, out_w, out_b, (float*)d_out);
}